// Round 1
// baseline (9628.585 us; speedup 1.0000x reference)
//
#include <hip/hip_runtime.h>
#include <hip/hip_bf16.h>
#include <stdint.h>

#define TLEN 2048
#define CDIM 2048
#define BDIM 2
#define HDIM 16
#define DHEAD 128

typedef __bf16 bf16x8 __attribute__((ext_vector_type(8)));
typedef float f32x4 __attribute__((ext_vector_type(4)));

__device__ __forceinline__ uint16_t f32_to_bf16(float f) {
    uint32_t u = __builtin_bit_cast(uint32_t, f);
    uint32_t r = (u + 0x7FFFu + ((u >> 16) & 1u)) >> 16;
    return (uint16_t)r;
}
__device__ __forceinline__ float bf16_to_f32(uint32_t h) {
    uint32_t u = h << 16;
    return __builtin_bit_cast(float, u);
}

// ---------------- elementwise f32 -> bf16 ----------------
__global__ void cvt_f32_bf16(const float* __restrict__ in, uint16_t* __restrict__ out, int n) {
    int i = (blockIdx.x * blockDim.x + threadIdx.x) * 4;
    if (i + 3 < n) {
        float4 f = *reinterpret_cast<const float4*>(in + i);
        ushort4 o;
        o.x = f32_to_bf16(f.x);
        o.y = f32_to_bf16(f.y);
        o.z = f32_to_bf16(f.z);
        o.w = f32_to_bf16(f.w);
        *reinterpret_cast<ushort4*>(out + i) = o;
    }
}

// ---------------- transpose + cast: in [R][Cc] f32 -> out [Cc][R] bf16 ----------------
__global__ __launch_bounds__(256) void transpose_cvt(const float* __restrict__ in,
                                                     uint16_t* __restrict__ out,
                                                     int R, int Cc) {
    __shared__ uint16_t tile[64][65];
    int c0 = blockIdx.x * 64;
    int r0 = blockIdx.y * 64;
    int tc = threadIdx.x & 63;
    int t4 = threadIdx.x >> 6;  // 0..3
    for (int rr = t4; rr < 64; rr += 4) {
        tile[rr][tc] = f32_to_bf16(in[(size_t)(r0 + rr) * Cc + c0 + tc]);
    }
    __syncthreads();
    int wr = threadIdx.x & 63;  // index along R (coalesced writes)
    for (int cc = t4; cc < 64; cc += 4) {
        out[(size_t)(c0 + cc) * R + r0 + wr] = tile[wr][cc];
    }
}

// ---------------- bf16 MFMA GEMM: C[M][N] = A[M][K] * Bt[N][K]^T ----------------
// Block: 256 threads = 4 waves, 64x64 tile, BK=32. Wave w -> 32x32 quadrant.
// mfma_f32_16x16x32_bf16 layouts (HW-verified per guide):
//   A frag: m = lane&15, k = (lane>>4)*8 + j
//   B frag: n = lane&15, k = (lane>>4)*8 + j
//   C/D:    col = lane&15, row = (lane>>4)*4 + reg
template <int OUT_BF16>
__global__ __launch_bounds__(256) void gemm_bf16(const uint16_t* __restrict__ A,
                                                 const uint16_t* __restrict__ Bt,
                                                 void* __restrict__ Cp,
                                                 int M, int N, int K) {
    __shared__ __align__(16) uint16_t As[64][32];
    __shared__ __align__(16) uint16_t Bs[64][32];
    int m0 = blockIdx.y * 64;
    int n0 = blockIdx.x * 64;
    int tid = threadIdx.x;
    int wave = tid >> 6;
    int lane = tid & 63;
    int wm = (wave >> 1) * 32;
    int wn = (wave & 1) * 32;
    int lrow = lane & 15;
    int quad = lane >> 4;

    f32x4 acc[2][2] = {};

    int ldrow = tid >> 2;        // 0..63
    int ldcol = (tid & 3) * 8;   // 0,8,16,24

    const uint16_t* Aload = A + (size_t)(m0 + ldrow) * K + ldcol;
    const uint16_t* Bload = Bt + (size_t)(n0 + ldrow) * K + ldcol;

    for (int k0 = 0; k0 < K; k0 += 32) {
        *reinterpret_cast<uint4*>(&As[ldrow][ldcol]) =
            *reinterpret_cast<const uint4*>(Aload + k0);
        *reinterpret_cast<uint4*>(&Bs[ldrow][ldcol]) =
            *reinterpret_cast<const uint4*>(Bload + k0);
        __syncthreads();
        bf16x8 afrag[2], bfrag[2];
        afrag[0] = *reinterpret_cast<const bf16x8*>(&As[wm + lrow][quad * 8]);
        afrag[1] = *reinterpret_cast<const bf16x8*>(&As[wm + 16 + lrow][quad * 8]);
        bfrag[0] = *reinterpret_cast<const bf16x8*>(&Bs[wn + lrow][quad * 8]);
        bfrag[1] = *reinterpret_cast<const bf16x8*>(&Bs[wn + 16 + lrow][quad * 8]);
#pragma unroll
        for (int mi = 0; mi < 2; mi++)
#pragma unroll
            for (int ni = 0; ni < 2; ni++)
                acc[mi][ni] = __builtin_amdgcn_mfma_f32_16x16x32_bf16(
                    afrag[mi], bfrag[ni], acc[mi][ni], 0, 0, 0);
        __syncthreads();
    }

#pragma unroll
    for (int mi = 0; mi < 2; mi++)
#pragma unroll
        for (int ni = 0; ni < 2; ni++)
#pragma unroll
            for (int r = 0; r < 4; r++) {
                int row = m0 + wm + mi * 16 + quad * 4 + r;
                int col = n0 + wn + ni * 16 + lrow;
                float v = acc[mi][ni][r];
                if (OUT_BF16)
                    ((uint16_t*)Cp)[(size_t)row * N + col] = f32_to_bf16(v);
                else
                    ((float*)Cp)[(size_t)row * N + col] = v;
            }
}

// ---------------- causal attention, online softmax ----------------
// qkv: [B*T][3C] bf16 (q at col h*128+d, k at 2048+..., v at 4096+...)
// One wave per (16-query tile, head, batch). Lane l owns dims {2l, 2l+1}.
__global__ __launch_bounds__(64) void attn_kernel(const uint16_t* __restrict__ qkv,
                                                  uint16_t* __restrict__ y) {
    int q0 = blockIdx.x * 16;
    int h = blockIdx.y;
    int b = blockIdx.z;
    int lane = threadIdx.x;
    const float scale = 0.08838834764831845f;  // 1/sqrt(128)
    const int ROW = 3 * CDIM;
    int dcol = h * DHEAD + lane * 2;

    float2 qr[16];
#pragma unroll
    for (int qi = 0; qi < 16; qi++) {
        const uint16_t* p = qkv + (size_t)(b * TLEN + q0 + qi) * ROW + dcol;
        uint32_t w = *reinterpret_cast<const uint32_t*>(p);
        qr[qi].x = bf16_to_f32(w & 0xffffu) * scale;
        qr[qi].y = bf16_to_f32(w >> 16) * scale;
    }

    float mM[16], lS[16];
    float2 accv[16];
#pragma unroll
    for (int qi = 0; qi < 16; qi++) {
        mM[qi] = -3.0e38f;
        lS[qi] = 0.0f;
        accv[qi] = make_float2(0.0f, 0.0f);
    }

    int jend = q0 + 16;
    for (int j = 0; j < jend; j++) {
        const uint16_t* kp = qkv + (size_t)(b * TLEN + j) * ROW + CDIM + dcol;
        uint32_t kw = *reinterpret_cast<const uint32_t*>(kp);
        uint32_t vw = *reinterpret_cast<const uint32_t*>(kp + CDIM);
        float k0 = bf16_to_f32(kw & 0xffffu), k1 = bf16_to_f32(kw >> 16);
        float v0 = bf16_to_f32(vw & 0xffffu), v1 = bf16_to_f32(vw >> 16);
#pragma unroll
        for (int qi = 0; qi < 16; qi++) {
            float s = qr[qi].x * k0 + qr[qi].y * k1;
            s += __shfl_xor(s, 1);
            s += __shfl_xor(s, 2);
            s += __shfl_xor(s, 4);
            s += __shfl_xor(s, 8);
            s += __shfl_xor(s, 16);
            s += __shfl_xor(s, 32);
            if (j > q0 + qi) s = -3.0e38f;
            float mnew = fmaxf(mM[qi], s);
            float alpha = __expf(mM[qi] - mnew);
            float p = __expf(s - mnew);
            mM[qi] = mnew;
            lS[qi] = lS[qi] * alpha + p;
            accv[qi].x = accv[qi].x * alpha + p * v0;
            accv[qi].y = accv[qi].y * alpha + p * v1;
        }
    }

#pragma unroll
    for (int qi = 0; qi < 16; qi++) {
        float inv = 1.0f / lS[qi];
        uint32_t lo = f32_to_bf16(accv[qi].x * inv);
        uint32_t hi = f32_to_bf16(accv[qi].y * inv);
        uint16_t* yp = y + (size_t)(b * TLEN + q0 + qi) * CDIM + dcol;
        *reinterpret_cast<uint32_t*>(yp) = lo | (hi << 16);
    }
}

extern "C" void kernel_launch(void* const* d_in, const int* in_sizes, int n_in,
                              void* d_out, int out_size, void* d_ws, size_t ws_size,
                              hipStream_t stream) {
    const float* x = (const float*)d_in[0];       // [2,2048,2048]
    const float* w_attn = (const float*)d_in[1];  // [2048, 6144]
    const float* w_proj = (const float*)d_in[2];  // [2048, 2048]
    float* out = (float*)d_out;                   // [2,2048,2048]

    const int M = BDIM * TLEN;  // 4096
    const int K = CDIM;         // 2048
    const int N3 = 3 * CDIM;    // 6144

    char* ws = (char*)d_ws;
    uint16_t* xb = (uint16_t*)(ws);                      // 16 MB: x bf16 [4096][2048]
    uint16_t* waT = (uint16_t*)(ws + 16777216);          // 24 MB: w_attn^T bf16 [6144][2048]
    uint16_t* wpT = (uint16_t*)(ws + 41943040);          // 8 MB: w_proj^T bf16 [2048][2048]
    uint16_t* qkvb = (uint16_t*)(ws + 50331648);         // 48 MB: qkv bf16 [4096][6144]
    uint16_t* yb = (uint16_t*)(ws + 100663296);          // 16 MB: y bf16 [4096][2048]

    // 1. cast x to bf16
    cvt_f32_bf16<<<(M * K / 4 + 255) / 256, 256, 0, stream>>>(x, xb, M * K);
    // 2. transpose+cast weights
    transpose_cvt<<<dim3(N3 / 64, K / 64), 256, 0, stream>>>(w_attn, waT, K, N3);
    transpose_cvt<<<dim3(K / 64, K / 64), 256, 0, stream>>>(w_proj, wpT, K, K);
    // 3. qkv = x @ w_attn   [4096][6144] bf16
    gemm_bf16<1><<<dim3(N3 / 64, M / 64), 256, 0, stream>>>(xb, waT, (void*)qkvb, M, N3, K);
    // 4. attention -> y bf16 [4096][2048]
    attn_kernel<<<dim3(TLEN / 16, HDIM, BDIM), 64, 0, stream>>>(qkvb, yb);
    // 5. out = y @ w_proj   fp32 [4096][2048]
    gemm_bf16<0><<<dim3(K / 64, M / 64), 256, 0, stream>>>(yb, wpT, (void*)out, M, K, K);
}

// Round 2
// 657.572 us; speedup vs baseline: 14.6426x; 14.6426x over previous
//
#include <hip/hip_runtime.h>
#include <hip/hip_bf16.h>
#include <stdint.h>

#define TLEN 2048
#define CDIM 2048
#define BDIM 2
#define HDIM 16
#define DHEAD 128

typedef __bf16 bf16x8 __attribute__((ext_vector_type(8)));
typedef float f32x4 __attribute__((ext_vector_type(4)));

__device__ __forceinline__ uint16_t f32_to_bf16(float f) {
    uint32_t u = __builtin_bit_cast(uint32_t, f);
    uint32_t r = (u + 0x7FFFu + ((u >> 16) & 1u)) >> 16;
    return (uint16_t)r;
}
__device__ __forceinline__ float bf16_to_f32(uint32_t h) {
    uint32_t u = h << 16;
    return __builtin_bit_cast(float, u);
}

// ---------------- elementwise f32 -> bf16 ----------------
__global__ void cvt_f32_bf16(const float* __restrict__ in, uint16_t* __restrict__ out, int n) {
    int i = (blockIdx.x * blockDim.x + threadIdx.x) * 4;
    if (i + 3 < n) {
        float4 f = *reinterpret_cast<const float4*>(in + i);
        ushort4 o;
        o.x = f32_to_bf16(f.x);
        o.y = f32_to_bf16(f.y);
        o.z = f32_to_bf16(f.z);
        o.w = f32_to_bf16(f.w);
        *reinterpret_cast<ushort4*>(out + i) = o;
    }
}

// ---------------- transpose + cast: in [R][Cc] f32 -> out [Cc][R] bf16 ----------------
__global__ __launch_bounds__(256) void transpose_cvt(const float* __restrict__ in,
                                                     uint16_t* __restrict__ out,
                                                     int R, int Cc) {
    __shared__ uint16_t tile[64][65];
    int c0 = blockIdx.x * 64;
    int r0 = blockIdx.y * 64;
    int tc = threadIdx.x & 63;
    int t4 = threadIdx.x >> 6;  // 0..3
    for (int rr = t4; rr < 64; rr += 4) {
        tile[rr][tc] = f32_to_bf16(in[(size_t)(r0 + rr) * Cc + c0 + tc]);
    }
    __syncthreads();
    int wr = threadIdx.x & 63;  // index along R (coalesced writes)
    for (int cc = t4; cc < 64; cc += 4) {
        out[(size_t)(c0 + cc) * R + r0 + wr] = tile[wr][cc];
    }
}

// ---------------- bf16 MFMA GEMM: C[M][N] = A[M][K] * Bt[N][K]^T ----------------
// Verified layouts (round 0 passed):
//   A frag: m = lane&15, k = (lane>>4)*8 + j
//   B frag: n = lane&15, k = (lane>>4)*8 + j
//   C/D:    col = lane&15, row = (lane>>4)*4 + reg
template <int OUT_BF16>
__global__ __launch_bounds__(256) void gemm_bf16(const uint16_t* __restrict__ A,
                                                 const uint16_t* __restrict__ Bt,
                                                 void* __restrict__ Cp,
                                                 int M, int N, int K) {
    __shared__ __align__(16) uint16_t As[64][32];
    __shared__ __align__(16) uint16_t Bs[64][32];
    int m0 = blockIdx.y * 64;
    int n0 = blockIdx.x * 64;
    int tid = threadIdx.x;
    int wave = tid >> 6;
    int lane = tid & 63;
    int wm = (wave >> 1) * 32;
    int wn = (wave & 1) * 32;
    int lrow = lane & 15;
    int quad = lane >> 4;

    f32x4 acc[2][2] = {};

    int ldrow = tid >> 2;        // 0..63
    int ldcol = (tid & 3) * 8;   // 0,8,16,24

    const uint16_t* Aload = A + (size_t)(m0 + ldrow) * K + ldcol;
    const uint16_t* Bload = Bt + (size_t)(n0 + ldrow) * K + ldcol;

    for (int k0 = 0; k0 < K; k0 += 32) {
        *reinterpret_cast<uint4*>(&As[ldrow][ldcol]) =
            *reinterpret_cast<const uint4*>(Aload + k0);
        *reinterpret_cast<uint4*>(&Bs[ldrow][ldcol]) =
            *reinterpret_cast<const uint4*>(Bload + k0);
        __syncthreads();
        bf16x8 afrag[2], bfrag[2];
        afrag[0] = *reinterpret_cast<const bf16x8*>(&As[wm + lrow][quad * 8]);
        afrag[1] = *reinterpret_cast<const bf16x8*>(&As[wm + 16 + lrow][quad * 8]);
        bfrag[0] = *reinterpret_cast<const bf16x8*>(&Bs[wn + lrow][quad * 8]);
        bfrag[1] = *reinterpret_cast<const bf16x8*>(&Bs[wn + 16 + lrow][quad * 8]);
#pragma unroll
        for (int mi = 0; mi < 2; mi++)
#pragma unroll
            for (int ni = 0; ni < 2; ni++)
                acc[mi][ni] = __builtin_amdgcn_mfma_f32_16x16x32_bf16(
                    afrag[mi], bfrag[ni], acc[mi][ni], 0, 0, 0);
        __syncthreads();
    }

#pragma unroll
    for (int mi = 0; mi < 2; mi++)
#pragma unroll
        for (int ni = 0; ni < 2; ni++)
#pragma unroll
            for (int r = 0; r < 4; r++) {
                int row = m0 + wm + mi * 16 + quad * 4 + r;
                int col = n0 + wn + ni * 16 + lrow;
                float v = acc[mi][ni][r];
                if (OUT_BF16)
                    ((uint16_t*)Cp)[(size_t)row * N + col] = f32_to_bf16(v);
                else
                    ((float*)Cp)[(size_t)row * N + col] = v;
            }
}

// ---------------- MFMA flash attention ----------------
// Block = 4 waves, owns (b, h, 64-query tile). Wave w owns queries
// qbase..qbase+15. Iterates 64-key tiles with online softmax.
// LDS: Ks [64 keys][128 dims] padded to 136 (2-way-free, 16B rows)
//      Vt [128 dims][64 keys] padded to 72  (transposed V for PV B-frags)
//      Ps [wave][16 q][64 keys] padded to 72 (P round-trip C->A layout)
__global__ __launch_bounds__(256) void attn_mfma(const uint16_t* __restrict__ qkv,
                                                 uint16_t* __restrict__ y) {
    __shared__ __align__(16) uint16_t Ks[64][136];
    __shared__ __align__(16) uint16_t Vt[128][72];
    __shared__ __align__(16) uint16_t Ps[4][16][72];

    const int qt = gridDim.x - 1 - blockIdx.x;  // heavy tiles dispatch first
    const int h = blockIdx.y;
    const int b = blockIdx.z;
    const int q0 = qt * 64;
    const int tid = threadIdx.x;
    const int wave = tid >> 6;
    const int lane = tid & 63;
    const int l15 = lane & 15;
    const int quad = lane >> 4;
    const int qbase = q0 + wave * 16;
    const float scale = 0.08838834764831845f;  // 1/sqrt(128)
    const size_t ROW = 3 * CDIM;

    // Q fragments (A-layout), 4 k-chunks of 32 dims
    bf16x8 qfrag[4];
    {
        const uint16_t* qptr =
            qkv + (size_t)(b * TLEN + qbase + l15) * ROW + h * DHEAD + quad * 8;
#pragma unroll
        for (int kc = 0; kc < 4; kc++)
            qfrag[kc] = *reinterpret_cast<const bf16x8*>(qptr + kc * 32);
    }

    f32x4 oacc[8] = {};  // 16 q x 128 d output accumulator (C-layout)
    float mrow[4], lrow[4];
#pragma unroll
    for (int r = 0; r < 4; r++) { mrow[r] = -1e30f; lrow[r] = 0.f; }

    const int ntiles = qt + 1;
    const int srow = tid >> 2;        // K staging: row 0..63
    const int scol = (tid & 3) * 8;   // 4 threads/row, 8 halves each
    const int vj = tid & 63;          // V staging: key index
    const int vd = (tid >> 6) * 32;   // dim base

    for (int tile = 0; tile < ntiles; ++tile) {
        const int j0 = tile * 64;
        if (tile > 0) __syncthreads();  // all waves done with previous tile
        // ---- stage K tile (coalesced) ----
        {
            const uint16_t* kbase =
                qkv + (size_t)(b * TLEN + j0 + srow) * ROW + CDIM + h * DHEAD;
#pragma unroll
            for (int pass = 0; pass < 4; pass++)
                *reinterpret_cast<uint4*>(&Ks[srow][scol + pass * 32]) =
                    *reinterpret_cast<const uint4*>(kbase + scol + pass * 32);
        }
        // ---- stage V tile transposed ----
        {
            const uint16_t* vbase =
                qkv + (size_t)(b * TLEN + j0 + vj) * ROW + 2 * CDIM + h * DHEAD + vd;
#pragma unroll
            for (int pass = 0; pass < 4; pass++) {
                uint4 vv = *reinterpret_cast<const uint4*>(vbase + pass * 8);
                const uint16_t* ve = reinterpret_cast<const uint16_t*>(&vv);
#pragma unroll
                for (int e = 0; e < 8; e++)
                    Vt[vd + pass * 8 + e][vj] = ve[e];
            }
        }
        __syncthreads();

        if (j0 > qbase + 15) continue;  // tile fully masked for this wave

        // ---- S = Q K^T : 4 n-chunks x 4 k-chunks ----
        f32x4 sacc[4] = {};
#pragma unroll
        for (int kc = 0; kc < 4; kc++)
#pragma unroll
            for (int n0 = 0; n0 < 4; n0++) {
                bf16x8 kfrag = *reinterpret_cast<const bf16x8*>(
                    &Ks[n0 * 16 + l15][kc * 32 + quad * 8]);
                sacc[n0] = __builtin_amdgcn_mfma_f32_16x16x32_bf16(
                    qfrag[kc], kfrag, sacc[n0], 0, 0, 0);
            }

        // ---- scale + causal mask ----
        const bool needMask = (j0 + 63 > qbase);
        float sc[4][4];
#pragma unroll
        for (int n0 = 0; n0 < 4; n0++)
#pragma unroll
            for (int r = 0; r < 4; r++) {
                float s = sacc[n0][r] * scale;
                if (needMask) {
                    int j = j0 + n0 * 16 + l15;
                    int q = qbase + quad * 4 + r;
                    if (j > q) s = -1e30f;
                }
                sc[n0][r] = s;
            }

        // ---- online softmax: row max (quad-local shuffle reduce) ----
        float alpha[4], rowsum[4];
#pragma unroll
        for (int r = 0; r < 4; r++) {
            float rm = fmaxf(fmaxf(sc[0][r], sc[1][r]), fmaxf(sc[2][r], sc[3][r]));
            rm = fmaxf(rm, __shfl_xor(rm, 1));
            rm = fmaxf(rm, __shfl_xor(rm, 2));
            rm = fmaxf(rm, __shfl_xor(rm, 4));
            rm = fmaxf(rm, __shfl_xor(rm, 8));
            float mnew = fmaxf(mrow[r], rm);
            alpha[r] = __expf(mrow[r] - mnew);
            mrow[r] = mnew;
            rowsum[r] = 0.f;
        }
        // ---- P = exp(S - m), write bf16 to per-wave LDS (C-layout) ----
#pragma unroll
        for (int n0 = 0; n0 < 4; n0++)
#pragma unroll
            for (int r = 0; r < 4; r++) {
                float p = __expf(sc[n0][r] - mrow[r]);
                uint16_t pb = f32_to_bf16(p);
                rowsum[r] += bf16_to_f32(pb);  // l consistent with quantized P
                Ps[wave][quad * 4 + r][n0 * 16 + l15] = pb;
            }
#pragma unroll
        for (int r = 0; r < 4; r++) {
            float rs = rowsum[r];
            rs += __shfl_xor(rs, 1);
            rs += __shfl_xor(rs, 2);
            rs += __shfl_xor(rs, 4);
            rs += __shfl_xor(rs, 8);
            lrow[r] = lrow[r] * alpha[r] + rs;
        }
        // ---- rescale O, then O += P V ----
#pragma unroll
        for (int n0 = 0; n0 < 8; n0++)
#pragma unroll
            for (int r = 0; r < 4; r++)
                oacc[n0][r] *= alpha[r];
        // same-wave DS ordering guarantees Ps write->read consistency
#pragma unroll
        for (int kc = 0; kc < 2; kc++) {
            bf16x8 pfrag = *reinterpret_cast<const bf16x8*>(
                &Ps[wave][l15][kc * 32 + quad * 8]);
#pragma unroll
            for (int n0 = 0; n0 < 8; n0++) {
                bf16x8 vfrag = *reinterpret_cast<const bf16x8*>(
                    &Vt[n0 * 16 + l15][kc * 32 + quad * 8]);
                oacc[n0] = __builtin_amdgcn_mfma_f32_16x16x32_bf16(
                    pfrag, vfrag, oacc[n0], 0, 0, 0);
            }
        }
    }

    // ---- epilogue: normalize, write y bf16 ----
    float invl[4];
#pragma unroll
    for (int r = 0; r < 4; r++) invl[r] = 1.0f / lrow[r];
    uint16_t* ybase = y + (size_t)(b * TLEN + qbase) * CDIM + h * DHEAD;
#pragma unroll
    for (int n0 = 0; n0 < 8; n0++)
#pragma unroll
        for (int r = 0; r < 4; r++)
            ybase[(size_t)(quad * 4 + r) * CDIM + n0 * 16 + l15] =
                f32_to_bf16(oacc[n0][r] * invl[r]);
}

extern "C" void kernel_launch(void* const* d_in, const int* in_sizes, int n_in,
                              void* d_out, int out_size, void* d_ws, size_t ws_size,
                              hipStream_t stream) {
    const float* x = (const float*)d_in[0];       // [2,2048,2048]
    const float* w_attn = (const float*)d_in[1];  // [2048, 6144]
    const float* w_proj = (const float*)d_in[2];  // [2048, 2048]
    float* out = (float*)d_out;                   // [2,2048,2048]

    const int M = BDIM * TLEN;  // 4096
    const int K = CDIM;         // 2048
    const int N3 = 3 * CDIM;    // 6144

    char* ws = (char*)d_ws;
    uint16_t* xb = (uint16_t*)(ws);                      // 16 MB: x bf16 [4096][2048]
    uint16_t* waT = (uint16_t*)(ws + 16777216);          // 24 MB: w_attn^T bf16 [6144][2048]
    uint16_t* wpT = (uint16_t*)(ws + 41943040);          // 8 MB: w_proj^T bf16 [2048][2048]
    uint16_t* qkvb = (uint16_t*)(ws + 50331648);         // 48 MB: qkv bf16 [4096][6144]
    uint16_t* yb = (uint16_t*)(ws + 100663296);          // 16 MB: y bf16 [4096][2048]

    // 1. cast x to bf16
    cvt_f32_bf16<<<(M * K / 4 + 255) / 256, 256, 0, stream>>>(x, xb, M * K);
    // 2. transpose+cast weights
    transpose_cvt<<<dim3(N3 / 64, K / 64), 256, 0, stream>>>(w_attn, waT, K, N3);
    transpose_cvt<<<dim3(K / 64, K / 64), 256, 0, stream>>>(w_proj, wpT, K, K);
    // 3. qkv = x @ w_attn   [4096][6144] bf16
    gemm_bf16<1><<<dim3(N3 / 64, M / 64), 256, 0, stream>>>(xb, waT, (void*)qkvb, M, N3, K);
    // 4. attention -> y bf16 [4096][2048]
    attn_mfma<<<dim3(TLEN / 64, HDIM, BDIM), 256, 0, stream>>>(qkvb, yb);
    // 5. out = y @ w_proj   fp32 [4096][2048]
    gemm_bf16<0><<<dim3(K / 64, M / 64), 256, 0, stream>>>(yb, wpT, (void*)out, M, K, K);
}

// Round 3
// 519.881 us; speedup vs baseline: 18.5207x; 1.2649x over previous
//
#include <hip/hip_runtime.h>
#include <hip/hip_bf16.h>
#include <stdint.h>

#define TLEN 2048
#define CDIM 2048
#define BDIM 2
#define HDIM 16
#define DHEAD 128

typedef __bf16 bf16x8 __attribute__((ext_vector_type(8)));
typedef float f32x4 __attribute__((ext_vector_type(4)));

__device__ __forceinline__ uint16_t f32_to_bf16(float f) {
    uint32_t u = __builtin_bit_cast(uint32_t, f);
    uint32_t r = (u + 0x7FFFu + ((u >> 16) & 1u)) >> 16;
    return (uint16_t)r;
}
__device__ __forceinline__ float bf16_to_f32(uint32_t h) {
    uint32_t u = h << 16;
    return __builtin_bit_cast(float, u);
}

// async global->LDS, 16B per lane. LDS dest = wave-uniform base + lane*16.
__device__ __forceinline__ void gload_lds16(const uint16_t* g, uint16_t* l) {
    __builtin_amdgcn_global_load_lds(
        (const __attribute__((address_space(1))) uint32_t*)g,
        (__attribute__((address_space(3))) uint32_t*)l, 16, 0, 0);
}

// ---------------- elementwise f32 -> bf16 ----------------
__global__ void cvt_f32_bf16(const float* __restrict__ in, uint16_t* __restrict__ out, int n) {
    int i = (blockIdx.x * blockDim.x + threadIdx.x) * 4;
    if (i + 3 < n) {
        float4 f = *reinterpret_cast<const float4*>(in + i);
        ushort4 o;
        o.x = f32_to_bf16(f.x);
        o.y = f32_to_bf16(f.y);
        o.z = f32_to_bf16(f.z);
        o.w = f32_to_bf16(f.w);
        *reinterpret_cast<ushort4*>(out + i) = o;
    }
}

// ---------------- transpose + cast: in [R][Cc] f32 -> out [Cc][R] bf16 ----------------
__global__ __launch_bounds__(256) void transpose_cvt(const float* __restrict__ in,
                                                     uint16_t* __restrict__ out,
                                                     int R, int Cc) {
    __shared__ uint16_t tile[64][65];
    int c0 = blockIdx.x * 64;
    int r0 = blockIdx.y * 64;
    int tc = threadIdx.x & 63;
    int t4 = threadIdx.x >> 6;  // 0..3
    for (int rr = t4; rr < 64; rr += 4) {
        tile[rr][tc] = f32_to_bf16(in[(size_t)(r0 + rr) * Cc + c0 + tc]);
    }
    __syncthreads();
    int wr = threadIdx.x & 63;  // index along R (coalesced writes)
    for (int cc = t4; cc < 64; cc += 4) {
        out[(size_t)(c0 + cc) * R + r0 + wr] = tile[wr][cc];
    }
}

// ---------------- m97-style bf16 MFMA GEMM: C[M][N] = A[M][K] * Bt[N][K]^T ----------------
// 256 threads = 4 waves; block tile 128x128; wave tile 64x64 (4x4 MFMA accs);
// BK=32; staging via global_load_lds width=16 into unpadded [128][32] LDS.
// Fragment layouts (HW-verified, rounds 0-2):
//   A/B frag: m/n = lane&15, k = (lane>>4)*8 + j
//   C/D:      col = lane&15, row = (lane>>4)*4 + reg
template <int OUT_BF16>
__global__ __launch_bounds__(256) void gemm_bf16_128(const uint16_t* __restrict__ A,
                                                     const uint16_t* __restrict__ Bt,
                                                     void* __restrict__ Cp,
                                                     int M, int N, int K) {
    __shared__ __align__(16) uint16_t As[128 * 32];
    __shared__ __align__(16) uint16_t Bs[128 * 32];
    const int tid = threadIdx.x;
    const int wave = tid >> 6;
    const int lane = tid & 63;
    const int l15 = lane & 15;
    const int quad = lane >> 4;
    const int m0 = blockIdx.y * 128;
    const int n0 = blockIdx.x * 128;
    const int wm = (wave >> 1) * 64;
    const int wn = (wave & 1) * 64;

    f32x4 acc[4][4] = {};

    // Staging: wave w owns slabs {2w, 2w+1}; slab s = rows s*16..s*16+15,
    // LDS offset s*512 halves. Lane i -> row s*16 + i/4, col (i%4)*8.
    const int s0 = wave * 2;
    const int lrow = lane >> 2;
    const int lcol = (lane & 3) * 8;
    const uint16_t* Ag = A + (size_t)(m0 + s0 * 16 + lrow) * K + lcol;
    const uint16_t* Bg = Bt + (size_t)(n0 + s0 * 16 + lrow) * K + lcol;
    uint16_t* AsW0 = As + s0 * 512;
    uint16_t* AsW1 = As + (s0 + 1) * 512;
    uint16_t* BsW0 = Bs + s0 * 512;
    uint16_t* BsW1 = Bs + (s0 + 1) * 512;
    const size_t rowStep = (size_t)16 * K;

    for (int k0 = 0; k0 < K; k0 += 32) {
        gload_lds16(Ag + k0, AsW0);
        gload_lds16(Ag + rowStep + k0, AsW1);
        gload_lds16(Bg + k0, BsW0);
        gload_lds16(Bg + rowStep + k0, BsW1);
        __syncthreads();  // drains vmcnt before barrier

        bf16x8 af[4], bfr[4];
#pragma unroll
        for (int mi = 0; mi < 4; mi++)
            af[mi] = *reinterpret_cast<const bf16x8*>(
                As + (wm + mi * 16 + l15) * 32 + quad * 8);
#pragma unroll
        for (int ni = 0; ni < 4; ni++)
            bfr[ni] = *reinterpret_cast<const bf16x8*>(
                Bs + (wn + ni * 16 + l15) * 32 + quad * 8);
#pragma unroll
        for (int mi = 0; mi < 4; mi++)
#pragma unroll
            for (int ni = 0; ni < 4; ni++)
                acc[mi][ni] = __builtin_amdgcn_mfma_f32_16x16x32_bf16(
                    af[mi], bfr[ni], acc[mi][ni], 0, 0, 0);
        __syncthreads();
    }

#pragma unroll
    for (int mi = 0; mi < 4; mi++)
#pragma unroll
        for (int ni = 0; ni < 4; ni++)
#pragma unroll
            for (int r = 0; r < 4; r++) {
                int row = m0 + wm + mi * 16 + quad * 4 + r;
                int col = n0 + wn + ni * 16 + l15;
                float v = acc[mi][ni][r];
                if (OUT_BF16)
                    ((uint16_t*)Cp)[(size_t)row * N + col] = f32_to_bf16(v);
                else
                    ((float*)Cp)[(size_t)row * N + col] = v;
            }
}

// ---------------- MFMA flash attention ----------------
// Block = 4 waves, owns (b, h, 64-query tile). Wave w owns queries
// qbase..qbase+15. Iterates 64-key tiles with online softmax.
__global__ __launch_bounds__(256) void attn_mfma(const uint16_t* __restrict__ qkv,
                                                 uint16_t* __restrict__ y) {
    __shared__ __align__(16) uint16_t Ks[64][136];
    __shared__ __align__(16) uint16_t Vt[128][72];
    __shared__ __align__(16) uint16_t Ps[4][16][72];

    const int qt = gridDim.x - 1 - blockIdx.x;  // heavy tiles dispatch first
    const int h = blockIdx.y;
    const int b = blockIdx.z;
    const int q0 = qt * 64;
    const int tid = threadIdx.x;
    const int wave = tid >> 6;
    const int lane = tid & 63;
    const int l15 = lane & 15;
    const int quad = lane >> 4;
    const int qbase = q0 + wave * 16;
    const float scale = 0.08838834764831845f;  // 1/sqrt(128)
    const size_t ROW = 3 * CDIM;

    bf16x8 qfrag[4];
    {
        const uint16_t* qptr =
            qkv + (size_t)(b * TLEN + qbase + l15) * ROW + h * DHEAD + quad * 8;
#pragma unroll
        for (int kc = 0; kc < 4; kc++)
            qfrag[kc] = *reinterpret_cast<const bf16x8*>(qptr + kc * 32);
    }

    f32x4 oacc[8] = {};
    float mrow[4], lrow[4];
#pragma unroll
    for (int r = 0; r < 4; r++) { mrow[r] = -1e30f; lrow[r] = 0.f; }

    const int ntiles = qt + 1;
    const int srow = tid >> 2;
    const int scol = (tid & 3) * 8;
    const int vj = tid & 63;
    const int vd = (tid >> 6) * 32;

    for (int tile = 0; tile < ntiles; ++tile) {
        const int j0 = tile * 64;
        if (tile > 0) __syncthreads();
        {
            const uint16_t* kbase =
                qkv + (size_t)(b * TLEN + j0 + srow) * ROW + CDIM + h * DHEAD;
#pragma unroll
            for (int pass = 0; pass < 4; pass++)
                *reinterpret_cast<uint4*>(&Ks[srow][scol + pass * 32]) =
                    *reinterpret_cast<const uint4*>(kbase + scol + pass * 32);
        }
        {
            const uint16_t* vbase =
                qkv + (size_t)(b * TLEN + j0 + vj) * ROW + 2 * CDIM + h * DHEAD + vd;
#pragma unroll
            for (int pass = 0; pass < 4; pass++) {
                uint4 vv = *reinterpret_cast<const uint4*>(vbase + pass * 8);
                const uint16_t* ve = reinterpret_cast<const uint16_t*>(&vv);
#pragma unroll
                for (int e = 0; e < 8; e++)
                    Vt[vd + pass * 8 + e][vj] = ve[e];
            }
        }
        __syncthreads();

        if (j0 > qbase + 15) continue;

        f32x4 sacc[4] = {};
#pragma unroll
        for (int kc = 0; kc < 4; kc++)
#pragma unroll
            for (int n0 = 0; n0 < 4; n0++) {
                bf16x8 kfrag = *reinterpret_cast<const bf16x8*>(
                    &Ks[n0 * 16 + l15][kc * 32 + quad * 8]);
                sacc[n0] = __builtin_amdgcn_mfma_f32_16x16x32_bf16(
                    qfrag[kc], kfrag, sacc[n0], 0, 0, 0);
            }

        const bool needMask = (j0 + 63 > qbase);
        float sc[4][4];
#pragma unroll
        for (int n0 = 0; n0 < 4; n0++)
#pragma unroll
            for (int r = 0; r < 4; r++) {
                float s = sacc[n0][r] * scale;
                if (needMask) {
                    int j = j0 + n0 * 16 + l15;
                    int q = qbase + quad * 4 + r;
                    if (j > q) s = -1e30f;
                }
                sc[n0][r] = s;
            }

        float alpha[4], rowsum[4];
#pragma unroll
        for (int r = 0; r < 4; r++) {
            float rm = fmaxf(fmaxf(sc[0][r], sc[1][r]), fmaxf(sc[2][r], sc[3][r]));
            rm = fmaxf(rm, __shfl_xor(rm, 1));
            rm = fmaxf(rm, __shfl_xor(rm, 2));
            rm = fmaxf(rm, __shfl_xor(rm, 4));
            rm = fmaxf(rm, __shfl_xor(rm, 8));
            float mnew = fmaxf(mrow[r], rm);
            alpha[r] = __expf(mrow[r] - mnew);
            mrow[r] = mnew;
            rowsum[r] = 0.f;
        }
#pragma unroll
        for (int n0 = 0; n0 < 4; n0++)
#pragma unroll
            for (int r = 0; r < 4; r++) {
                float p = __expf(sc[n0][r] - mrow[r]);
                uint16_t pb = f32_to_bf16(p);
                rowsum[r] += bf16_to_f32(pb);
                Ps[wave][quad * 4 + r][n0 * 16 + l15] = pb;
            }
#pragma unroll
        for (int r = 0; r < 4; r++) {
            float rs = rowsum[r];
            rs += __shfl_xor(rs, 1);
            rs += __shfl_xor(rs, 2);
            rs += __shfl_xor(rs, 4);
            rs += __shfl_xor(rs, 8);
            lrow[r] = lrow[r] * alpha[r] + rs;
        }
#pragma unroll
        for (int n0 = 0; n0 < 8; n0++)
#pragma unroll
            for (int r = 0; r < 4; r++)
                oacc[n0][r] *= alpha[r];
#pragma unroll
        for (int kc = 0; kc < 2; kc++) {
            bf16x8 pfrag = *reinterpret_cast<const bf16x8*>(
                &Ps[wave][l15][kc * 32 + quad * 8]);
#pragma unroll
            for (int n0 = 0; n0 < 8; n0++) {
                bf16x8 vfrag = *reinterpret_cast<const bf16x8*>(
                    &Vt[n0 * 16 + l15][kc * 32 + quad * 8]);
                oacc[n0] = __builtin_amdgcn_mfma_f32_16x16x32_bf16(
                    pfrag, vfrag, oacc[n0], 0, 0, 0);
            }
        }
    }

    float invl[4];
#pragma unroll
    for (int r = 0; r < 4; r++) invl[r] = 1.0f / lrow[r];
    uint16_t* ybase = y + (size_t)(b * TLEN + qbase) * CDIM + h * DHEAD;
#pragma unroll
    for (int n0 = 0; n0 < 8; n0++)
#pragma unroll
        for (int r = 0; r < 4; r++)
            ybase[(size_t)(quad * 4 + r) * CDIM + n0 * 16 + l15] =
                f32_to_bf16(oacc[n0][r] * invl[r]);
}

extern "C" void kernel_launch(void* const* d_in, const int* in_sizes, int n_in,
                              void* d_out, int out_size, void* d_ws, size_t ws_size,
                              hipStream_t stream) {
    const float* x = (const float*)d_in[0];       // [2,2048,2048]
    const float* w_attn = (const float*)d_in[1];  // [2048, 6144]
    const float* w_proj = (const float*)d_in[2];  // [2048, 2048]
    float* out = (float*)d_out;                   // [2,2048,2048]

    const int M = BDIM * TLEN;  // 4096
    const int K = CDIM;         // 2048
    const int N3 = 3 * CDIM;    // 6144

    char* ws = (char*)d_ws;
    uint16_t* xb = (uint16_t*)(ws);                      // 16 MB: x bf16 [4096][2048]
    uint16_t* waT = (uint16_t*)(ws + 16777216);          // 24 MB: w_attn^T bf16 [6144][2048]
    uint16_t* wpT = (uint16_t*)(ws + 41943040);          // 8 MB: w_proj^T bf16 [2048][2048]
    uint16_t* qkvb = (uint16_t*)(ws + 50331648);         // 48 MB: qkv bf16 [4096][6144]
    uint16_t* yb = (uint16_t*)(ws + 100663296);          // 16 MB: y bf16 [4096][2048]

    // 1. cast x to bf16
    cvt_f32_bf16<<<(M * K / 4 + 255) / 256, 256, 0, stream>>>(x, xb, M * K);
    // 2. transpose+cast weights
    transpose_cvt<<<dim3(N3 / 64, K / 64), 256, 0, stream>>>(w_attn, waT, K, N3);
    transpose_cvt<<<dim3(K / 64, K / 64), 256, 0, stream>>>(w_proj, wpT, K, K);
    // 3. qkv = x @ w_attn   [4096][6144] bf16
    gemm_bf16_128<1><<<dim3(N3 / 128, M / 128), 256, 0, stream>>>(xb, waT, (void*)qkvb, M, N3, K);
    // 4. attention -> y bf16 [4096][2048]
    attn_mfma<<<dim3(TLEN / 64, HDIM, BDIM), 256, 0, stream>>>(qkvb, yb);
    // 5. out = y @ w_proj   fp32 [4096][2048]
    gemm_bf16_128<0><<<dim3(K / 128, M / 128), 256, 0, stream>>>(yb, wpT, (void*)out, M, K, K);
}